// Round 2
// baseline (75.748 us; speedup 1.0000x reference)
//
#include <hip/hip_runtime.h>

// Tropical (max-plus) matmul: out[n,m] = max_k(|x[n,k]| + |w[m,k]|)
// N=1024, K=256, M=1024, fp32 in/out.
//
// Round 4. R3 (64x64 tile, full-K LDS, 4x4 blocking) measured ~30 us kernel
// (dur_us - 41 us poison fill), 3x worse than its LDS-traffic model. Fixes:
//  1. NO runtime-indexed arrays: R3's xo[kp&3]/wo[kp&3] under "#pragma
//     unroll 4" risks scratch allocation (rule #20). Now: explicit 4-phase
//     loop bodies with named compile-time swizzle variants (ty0..ty12).
//  2. Occupancy: R3 was 1 block/CU = 1 wave/SIMD (grid 256, 128 KB LDS),
//     fully exposing ds_read latency. Now: K split across 2 blocks
//     (grid 512, K=128 each, 64 KB LDS) -> 2 blocks/CU = 2 waves/SIMD.
//     Partials go to d_ws (256 MiB, per fill counter); a tiny second
//     kernel max-merges deterministically (no atomics, no init pass).
//  3. LDS bank conflicts: R3's 4-consecutive-cols blocking made w-reads
//     stride 32 B/lane -> 4-way conflict. Now stride-16 blocking: thread
//     owns rows/cols {t, t+16, t+32, t+48}; per kp a 16-lane group reads
//     16 consecutive 8-B slots -> each bank exactly once. The kp-phase XOR
//     (bits 2-3) commutes with +16j, so every LDS access is base + imm.
// Compute core unchanged (verified): v_pk_add_f32 + v_max3_f32, 16 chains.

typedef float v2f __attribute__((ext_vector_type(2)));
typedef float v4f __attribute__((ext_vector_type(4)));

constexpr int K    = 256;
constexpr int N    = 1024;
constexpr int M    = 1024;
constexpr int TILE = 64;
constexpr int KH   = 128;        // K per block (half)
constexpr int KPL  = KH / 2;     // 64 k-pairs per block

__global__ void __launch_bounds__(256, 2)
tropical_main(const float* __restrict__ xg, const float* __restrict__ wg,
              float* __restrict__ pw)
{
    __shared__ __align__(16) v2f xs[KPL * 64];   // 32 KB
    __shared__ __align__(16) v2f wsh[KPL * 64];  // 32 KB

    const int tid = threadIdx.x;
    const int tx  = tid & 15;          // m-side: cols bm + tx + 16b
    const int ty  = tid >> 4;          // n-side: rows bn + ty + 16a
    const int bt  = (int)blockIdx.x & 255;
    const int kh  = (int)blockIdx.x >> 8;        // 0/1: which K half
    const int bn  = (bt >> 4) * TILE;
    const int bm  = (bt & 15) * TILE;
    const int k0  = kh * KH;

    // Staging: thread covers rows {r0, r0+32}, v4f quads q = l + 8*i.
    // Global: 8 lanes x 16 B contiguous = 128-B segments (coalesced).
    const int r0 = tid >> 3;           // 0..31
    const int l  = tid & 7;            // 0..7
    const v4f* x0 = (const v4f*)(xg + (bn + r0     ) * K + k0);
    const v4f* x1 = (const v4f*)(xg + (bn + r0 + 32) * K + k0);
    const v4f* w0 = (const v4f*)(wg + (bm + r0     ) * K + k0);
    const v4f* w1 = (const v4f*)(wg + (bm + r0 + 32) * K + k0);

#pragma unroll
    for (int i = 0; i < 4; ++i) {
        const int q   = l + 8 * i;     // 0..31
        const int kpl = 2 * q;         // even kp row
        v4f a = x0[q];
        v4f b = x1[q];
        v4f c = w0[q];
        v4f d = w1[q];
        const int s0 = ((kpl    ) & 3) << 2;   // row-slot swizzle, bits 2-3
        const int s1 = ((kpl + 1) & 3) << 2;
        xs [(kpl    ) * 64 + ((r0     ) ^ s0)] = (v2f){fabsf(a.x), fabsf(a.y)};
        xs [(kpl + 1) * 64 + ((r0     ) ^ s1)] = (v2f){fabsf(a.z), fabsf(a.w)};
        xs [(kpl    ) * 64 + ((r0 + 32) ^ s0)] = (v2f){fabsf(b.x), fabsf(b.y)};
        xs [(kpl + 1) * 64 + ((r0 + 32) ^ s1)] = (v2f){fabsf(b.z), fabsf(b.w)};
        wsh[(kpl    ) * 64 + ((r0     ) ^ s0)] = (v2f){fabsf(c.x), fabsf(c.y)};
        wsh[(kpl + 1) * 64 + ((r0     ) ^ s1)] = (v2f){fabsf(c.z), fabsf(c.w)};
        wsh[(kpl    ) * 64 + ((r0 + 32) ^ s0)] = (v2f){fabsf(d.x), fabsf(d.y)};
        wsh[(kpl + 1) * 64 + ((r0 + 32) ^ s1)] = (v2f){fabsf(d.z), fabsf(d.w)};
    }

    __syncthreads();   // the only barrier

    // Sums are >= 0, so 0 is a safe max-identity.
    float acc[4][4];
#pragma unroll
    for (int a2 = 0; a2 < 4; ++a2)
#pragma unroll
        for (int b2 = 0; b2 < 4; ++b2) acc[a2][b2] = 0.f;

    // Phase-selected swizzled base slots: NAMED scalars, never arrays.
    const int ty0 = ty;        const int tx0 = tx;
    const int ty4 = ty ^ 4;    const int tx4 = tx ^ 4;
    const int ty8 = ty ^ 8;    const int tx8 = tx ^ 8;
    const int ty12 = ty ^ 12;  const int tx12 = tx ^ 12;

#define PHASE(J, TYJ, TXJ)                                                   \
    do {                                                                     \
        const v2f* xr = xs  + (kp4 + (J)) * 64;                              \
        const v2f* wr = wsh + (kp4 + (J)) * 64;                              \
        v2f xa[4] = {xr[(TYJ)], xr[(TYJ) + 16], xr[(TYJ) + 32], xr[(TYJ) + 48]}; \
        v2f wa[4] = {wr[(TXJ)], wr[(TXJ) + 16], wr[(TXJ) + 32], wr[(TXJ) + 48]}; \
        _Pragma("unroll")                                                    \
        for (int a2 = 0; a2 < 4; ++a2)                                       \
            _Pragma("unroll")                                                \
            for (int b2 = 0; b2 < 4; ++b2) {                                 \
                v2f s = xa[a2] + wa[b2];            /* v_pk_add_f32 */       \
                acc[a2][b2] = fmaxf(acc[a2][b2], fmaxf(s.x, s.y)); /* max3 */\
            }                                                                \
    } while (0)

    for (int kp4 = 0; kp4 < KPL; kp4 += 4) {
        PHASE(0, ty0,  tx0);
        PHASE(1, ty4,  tx4);
        PHASE(2, ty8,  tx8);
        PHASE(3, ty12, tx12);
    }
#undef PHASE

    // Partial-tile write: one K-half per ws slab. For fixed (a2,b2) a wave
    // stores 4 rows x 64 B contiguous -> coalesced.
    float* slab = pw + kh * (N * M);
#pragma unroll
    for (int a2 = 0; a2 < 4; ++a2)
#pragma unroll
        for (int b2 = 0; b2 < 4; ++b2)
            slab[(bn + ty + 16 * a2) * M + (bm + tx + 16 * b2)] = acc[a2][b2];
}

__global__ void __launch_bounds__(256)
tropical_merge(const float* __restrict__ pw, float* __restrict__ outg)
{
    const int i = (int)blockIdx.x * 256 + (int)threadIdx.x;   // v4f index
    v4f a = ((const v4f*)pw)[i];
    v4f b = ((const v4f*)(pw + N * M))[i];
    v4f m = {fmaxf(a.x, b.x), fmaxf(a.y, b.y),
             fmaxf(a.z, b.z), fmaxf(a.w, b.w)};
    ((v4f*)outg)[i] = m;
}

extern "C" void kernel_launch(void* const* d_in, const int* in_sizes, int n_in,
                              void* d_out, int out_size, void* d_ws, size_t ws_size,
                              hipStream_t stream)
{
    const float* x = (const float*)d_in[0];   // [1024, 256]
    const float* w = (const float*)d_in[1];   // [1024, 256]
    float* out = (float*)d_out;               // [1024, 1024]
    float* ws  = (float*)d_ws;                // >= 8 MB needed, 256 MiB avail

    // Main: 256 tiles x 2 K-halves = 512 blocks = 2 blocks/CU (64 KB LDS each).
    tropical_main<<<dim3(512), dim3(256), 0, stream>>>(x, w, ws);
    // Merge the two 4-MB partial slabs into out (stream-ordered).
    tropical_merge<<<dim3(N * M / 4 / 256), dim3(256), 0, stream>>>(ws, out);
}

// Round 3
// 71.593 us; speedup vs baseline: 1.0580x; 1.0580x over previous
//
#include <hip/hip_runtime.h>

// Tropical (max-plus) matmul: out[n,m] = max_k(|x[n,k]| + |w[m,k]|)
// N=1024, K=256, M=1024, fp32 in/out.
//
// Round 5. R4's split-K across blocks regressed +3 us = merge dispatch +
// 12 MB HBM + extra launch. This round folds the split INSIDE one block:
//  - 64x64 tile, 512 threads: waves 0-3 take K[0:128), waves 4-7 take
//    K[128:256). Full K resident (128 KB LDS), ONE staging barrier,
//    grid 256 = 1 block/CU, 8 waves/CU = 2 waves/SIMD (latency cover).
//  - Merge is in-LDS: high half writes its 4x4 partials into a 16-KB
//    region reusing xs (after a barrier - all tile reads are done), low
//    half maxes and stores. No second kernel, no workspace traffic.
//  - Kept from R4: stride-16 register blocking (per-kp w-reads touch each
//    bank exactly once; x-reads are 16-lane broadcasts = near-free),
//    kp-phase XOR swizzle with NAMED compile-time offsets (no
//    runtime-indexed arrays -> no scratch), v_pk_add_f32 + v_max3_f32 core.

typedef float v2f __attribute__((ext_vector_type(2)));
typedef float v4f __attribute__((ext_vector_type(4)));

constexpr int K    = 256;
constexpr int N    = 1024;
constexpr int M    = 1024;
constexpr int TILE = 64;
constexpr int KP   = K / 2;      // 128 k-pair rows resident

__global__ void __launch_bounds__(512, 2)
tropical_kernel(const float* __restrict__ xg, const float* __restrict__ wg,
                float* __restrict__ outg)
{
    __shared__ __align__(16) v2f xs[KP * 64];    // 64 KB
    __shared__ __align__(16) v2f wsh[KP * 64];   // 64 KB

    const int tid = threadIdx.x;
    const int bn  = (int)(blockIdx.x >> 4) * TILE;
    const int bm  = (int)(blockIdx.x & 15) * TILE;

    // ---- Staging: 512 threads cover 64 rows x 64 quads per side. ----
    // Global: 8 lanes x 16 B contiguous = 128-B segments (coalesced).
    const int r0 = tid >> 3;     // 0..63
    const int l  = tid & 7;      // 0..7
    const float* xrow = xg + (bn + r0) * K;
    const float* wrow = wg + (bm + r0) * K;

#pragma unroll
    for (int i = 0; i < 8; ++i) {
        const int q  = l + 8 * i;        // quad 0..63
        const int kp = 2 * q;            // even kp row
        v4f a = *(const v4f*)(xrow + 4 * q);
        v4f c = *(const v4f*)(wrow + 4 * q);
        const int s0 = ((kp    ) & 3) << 2;   // row-slot swizzle, bits 2-3
        const int s1 = ((kp + 1) & 3) << 2;
        xs [(kp    ) * 64 + (r0 ^ s0)] = (v2f){fabsf(a.x), fabsf(a.y)};
        xs [(kp + 1) * 64 + (r0 ^ s1)] = (v2f){fabsf(a.z), fabsf(a.w)};
        wsh[(kp    ) * 64 + (r0 ^ s0)] = (v2f){fabsf(c.x), fabsf(c.y)};
        wsh[(kp + 1) * 64 + (r0 ^ s1)] = (v2f){fabsf(c.z), fabsf(c.w)};
    }

    __syncthreads();   // tile resident

    // ---- Compute: th = output thread (4x4 at stride 16), half = K half. ----
    const int th   = tid & 255;
    const int half = tid >> 8;           // wave-uniform (waves 0-3 vs 4-7)
    const int tx   = th & 15;            // cols bm + tx + 16*b2
    const int ty   = th >> 4;            // rows bn + ty + 16*a2

    // Sums are >= 0, so 0 is a safe max-identity.
    float acc[4][4];
#pragma unroll
    for (int a2 = 0; a2 < 4; ++a2)
#pragma unroll
        for (int b2 = 0; b2 < 4; ++b2) acc[a2][b2] = 0.f;

    // Phase-selected swizzled base slots: NAMED scalars, never arrays.
    // XOR hits bits 2-3 only; +16*j lives in bits >=4, so it commutes.
    const int ty0  = ty;       const int tx0  = tx;
    const int ty4  = ty ^ 4;   const int tx4  = tx ^ 4;
    const int ty8  = ty ^ 8;   const int tx8  = tx ^ 8;
    const int ty12 = ty ^ 12;  const int tx12 = tx ^ 12;

#define PHASE(J, TYJ, TXJ)                                                   \
    do {                                                                     \
        const v2f* xr = xs  + (kp4 + (J)) * 64;                              \
        const v2f* wr = wsh + (kp4 + (J)) * 64;                              \
        v2f xa[4] = {xr[(TYJ)], xr[(TYJ) + 16], xr[(TYJ) + 32], xr[(TYJ) + 48]}; \
        v2f wa[4] = {wr[(TXJ)], wr[(TXJ) + 16], wr[(TXJ) + 32], wr[(TXJ) + 48]}; \
        _Pragma("unroll")                                                    \
        for (int a2 = 0; a2 < 4; ++a2)                                       \
            _Pragma("unroll")                                                \
            for (int b2 = 0; b2 < 4; ++b2) {                                 \
                v2f s = xa[a2] + wa[b2];            /* v_pk_add_f32 */       \
                acc[a2][b2] = fmaxf(acc[a2][b2], fmaxf(s.x, s.y)); /* max3 */\
            }                                                                \
    } while (0)

    const int kbeg = half * 64;          // kp range for this K half
    for (int kp4 = kbeg; kp4 < kbeg + 64; kp4 += 4) {
        PHASE(0, ty0,  tx0);
        PHASE(1, ty4,  tx4);
        PHASE(2, ty8,  tx8);
        PHASE(3, ty12, tx12);
    }
#undef PHASE

    // ---- In-LDS merge of the two K halves (reuse xs: 16 KB needed). ----
    __syncthreads();                     // all xs/wsh tile reads complete
    v4f* mb = (v4f*)xs;                  // [4][256] v4f slots
    if (half == 1) {
#pragma unroll
        for (int a2 = 0; a2 < 4; ++a2)
            mb[a2 * 256 + th] =
                (v4f){acc[a2][0], acc[a2][1], acc[a2][2], acc[a2][3]};
    }
    __syncthreads();
    if (half == 0) {
#pragma unroll
        for (int a2 = 0; a2 < 4; ++a2) {
            v4f o = mb[a2 * 256 + th];
            float m0 = fmaxf(acc[a2][0], o.x);
            float m1 = fmaxf(acc[a2][1], o.y);
            float m2 = fmaxf(acc[a2][2], o.z);
            float m3 = fmaxf(acc[a2][3], o.w);
            float* orow = outg + (bn + ty + 16 * a2) * M + bm;
            orow[tx     ] = m0;          // per instr: 16 lanes x 4 rows,
            orow[tx + 16] = m1;          // 64-B contiguous segments
            orow[tx + 32] = m2;
            orow[tx + 48] = m3;
        }
    }
}

extern "C" void kernel_launch(void* const* d_in, const int* in_sizes, int n_in,
                              void* d_out, int out_size, void* d_ws, size_t ws_size,
                              hipStream_t stream)
{
    const float* x = (const float*)d_in[0];   // [1024, 256]
    const float* w = (const float*)d_in[1];   // [1024, 256]
    float* out = (float*)d_out;               // [1024, 1024]

    dim3 grid(256);    // 16 x 16 tiles of 64x64, 1 block/CU
    dim3 block(512);   // 8 waves: 2 K-halves x 4 waves
    tropical_kernel<<<grid, block, 0, stream>>>(x, w, out);
}